// Round 2
// baseline (629.685 us; speedup 1.0000x reference)
//
#include <hip/hip_runtime.h>
#include <hip/hip_bf16.h>

// GINE on MI355X — fp32 inputs/outputs per reference dtype contract.
static const int NN = 100000;   // nodes
static const int NE = 1600000;  // edges
static const int NG = 512;      // graphs

typedef __attribute__((ext_vector_type(8))) short shortx8;
typedef __attribute__((ext_vector_type(4))) float floatx4;

__device__ __forceinline__ float bf2f(unsigned short u) {
  union { unsigned int i; float f; } v; v.i = ((unsigned int)u) << 16; return v.f;
}
__device__ __forceinline__ unsigned short f2bf(float f) {
  union { float f; unsigned int i; } v; v.f = f;
  return (unsigned short)((v.i + 0x7FFFu + ((v.i >> 16) & 1u)) >> 16);
}

// ---- CSR build ----------------------------------------------------------
__global__ void k_hist(const int* __restrict__ dst, int* __restrict__ counts) {
  int e = blockIdx.x * 256 + threadIdx.x;
  if (e < NE) atomicAdd(&counts[dst[e]], 1);
}

__global__ void k_scan1(const int* __restrict__ counts, int* __restrict__ offs,
                        int* __restrict__ bsums) {
  __shared__ int sh[256];
  int t = threadIdx.x;
  int base = blockIdx.x * 1024 + t * 4;
  int c0 = (base + 0 < NN) ? counts[base + 0] : 0;
  int c1 = (base + 1 < NN) ? counts[base + 1] : 0;
  int c2 = (base + 2 < NN) ? counts[base + 2] : 0;
  int c3 = (base + 3 < NN) ? counts[base + 3] : 0;
  int ts = c0 + c1 + c2 + c3;
  sh[t] = ts;
  __syncthreads();
  for (int d = 1; d < 256; d <<= 1) {
    int v = (t >= d) ? sh[t - d] : 0;
    __syncthreads();
    sh[t] += v;
    __syncthreads();
  }
  int run = sh[t] - ts;
  if (base + 0 < NN) offs[base + 0] = run;
  run += c0;
  if (base + 1 < NN) offs[base + 1] = run;
  run += c1;
  if (base + 2 < NN) offs[base + 2] = run;
  run += c2;
  if (base + 3 < NN) offs[base + 3] = run;
  if (t == 255) bsums[blockIdx.x] = sh[255];
}

__global__ void k_scan2(int* __restrict__ bsums, int nb) {
  __shared__ int sh[128];
  int t = threadIdx.x;
  int v = (t < nb) ? bsums[t] : 0;
  sh[t] = v;
  __syncthreads();
  for (int d = 1; d < 128; d <<= 1) {
    int u = (t >= d) ? sh[t - d] : 0;
    __syncthreads();
    sh[t] += u;
    __syncthreads();
  }
  if (t < nb) bsums[t] = sh[t] - v;
}

__global__ void k_scan3(int* __restrict__ offs, const int* __restrict__ bsums,
                        int* __restrict__ cursor) {
  int i = blockIdx.x * 256 + threadIdx.x;
  if (i < NN) {
    int o = offs[i] + bsums[i >> 10];
    offs[i] = o;
    cursor[i] = o;
  }
  if (i == 0) offs[NN] = NE;
}

// csr entry packed: src (17 bits) | (x_idx[src]*16 + edge_attr) << 17 (11 bits)
__global__ void k_fill(const int* __restrict__ src, const int* __restrict__ dstp,
                       const int* __restrict__ ea, const int* __restrict__ x_idx,
                       int* __restrict__ cursor, int* __restrict__ csr) {
  int e = blockIdx.x * 256 + threadIdx.x;
  if (e >= NE) return;
  int d = dstp[e];
  int p = atomicAdd(&cursor[d], 1);
  int s = src[e];
  csr[p] = s | ((x_idx[s] * 16 + ea[e]) << 17);
}

// ---- tiny precomputes (fp32) -------------------------------------------
__global__ void k_et(const float* __restrict__ bond,
                     const float* __restrict__ we0, const float* __restrict__ be0,
                     const float* __restrict__ we1, const float* __restrict__ be1,
                     float* __restrict__ et0, float* __restrict__ et1) {
  int i = blockIdx.x * 256 + threadIdx.x;
  if (i < 16 * 64) {
    int b = i >> 6, c = i & 63;
    float acc = be0[c];
    for (int k = 0; k < 64; ++k) acc += bond[b * 64 + k] * we0[k * 64 + c];
    et0[i] = acc;
  } else {
    int j = i - 1024;
    if (j < 16 * 128) {
      int b = j >> 7, c = j & 127;
      float acc = be1[c];
      for (int k = 0; k < 64; ++k) acc += bond[b * 64 + k] * we1[k * 128 + c];
      et1[j] = acc;
    }
  }
}

// M0[(a*16+b)*64+c] = relu(atom_emb[a][c] + et0[b][c]) -- all distinct L0 messages
__global__ void k_m0(const float* __restrict__ atom, const float* __restrict__ et0,
                     float* __restrict__ M0) {
  int i = blockIdx.x * 256 + threadIdx.x;
  if (i >= 119 * 16 * 64) return;
  int c = i & 63, b = (i >> 6) & 15, a = i >> 10;
  float v = atom[a * 64 + c] + et0[b * 64 + c];
  M0[i] = v > 0.f ? v : 0.f;
}

// fp32 weights -> bf16 MFMA B-frag order:
// wz[((s*8+ct)*64+lane)*8+j] = w[s*32+(lane>>4)*8+j][ct*16+(lane&15)]
__global__ void k_swz(const float* __restrict__ w, unsigned short* __restrict__ wz, int K) {
  int i = blockIdx.x * 256 + threadIdx.x;
  if (i >= K * 128) return;
  int j = i & 7, lane = (i >> 3) & 63, ct = (i >> 9) & 7, s = i >> 12;
  int k = s * 32 + (lane >> 4) * 8 + j;
  int m = ct * 16 + (lane & 15);
  wz[i] = f2bf(w[k * 128 + m]);
}

// ---- aggregation (gather, wave per node, lane = channel) ---------------
__global__ void k_agg0(const int* __restrict__ x_idx, const float* __restrict__ atom,
                       const float* __restrict__ M0, const int* __restrict__ offs,
                       const int* __restrict__ csr, unsigned short* __restrict__ h0) {
  int gt = blockIdx.x * 256 + threadIdx.x;
  int n = gt >> 6, lane = gt & 63;
  if (n >= NN) return;
  float acc = atom[x_idx[n] * 64 + lane];  // h = x + agg (eps=0)
  int s = offs[n], e = offs[n + 1];
  for (int i = s; i < e; ++i) {
    int pc = csr[i];
    acc += M0[(pc >> 17) * 64 + lane];  // relu already applied in table
  }
  h0[n * 64 + lane] = f2bf(acc);
}

__global__ void k_agg1(const unsigned short* __restrict__ x1, const float* __restrict__ et1,
                       const int* __restrict__ offs, const int* __restrict__ csr,
                       unsigned short* __restrict__ h1) {
  int gt = blockIdx.x * 256 + threadIdx.x;
  int n = gt >> 6, lane = gt & 63;  // lane handles channels 2c,2c+1
  if (n >= NN) return;
  unsigned int xv = *(const unsigned int*)(x1 + n * 128 + lane * 2);
  float ax = bf2f((unsigned short)(xv & 0xFFFF));
  float ay = bf2f((unsigned short)(xv >> 16));
  int s = offs[n], e = offs[n + 1];
  for (int i = s; i < e; ++i) {
    int pc = csr[i];
    int sn = pc & 0x1FFFF;
    int b = (pc >> 17) & 15;
    unsigned int v = *(const unsigned int*)(x1 + sn * 128 + lane * 2);
    float2 ef = *(const float2*)(et1 + b * 128 + lane * 2);
    float mx = bf2f((unsigned short)(v & 0xFFFF)) + ef.x;
    float my = bf2f((unsigned short)(v >> 16)) + ef.y;
    ax += mx > 0.f ? mx : 0.f;
    ay += my > 0.f ? my : 0.f;
  }
  unsigned int o = (unsigned int)f2bf(ax) | ((unsigned int)f2bf(ay) << 16);
  *(unsigned int*)(h1 + n * 128 + lane * 2) = o;
}

// ---- fused double-GEMM MLP: out = act2(act1(in@w1+b1)@w2+b2)
// in bf16 [N][K1]; w1z/w2z pre-swizzled bf16 frags; biases fp32; out bf16 or fp32.
// act: 0=none 1=elu 2=relu. Wave = 16 rows x 128 cols; GEMM1->LDS tile->GEMM2.
__global__ void k_mlp(const unsigned short* __restrict__ in, int K1,
                      const unsigned short* __restrict__ w1z, const float* __restrict__ b1,
                      const unsigned short* __restrict__ w2z, const float* __restrict__ b2,
                      unsigned short* __restrict__ outb, float* __restrict__ outf,
                      int N, int act1, int act2) {
  __shared__ unsigned short tls[4][16][128];
  int lane = threadIdx.x & 63;
  int wave = threadIdx.x >> 6;
  int row0 = blockIdx.x * 64 + wave * 16;
  int rlo = lane & 15, quad = lane >> 4;
  int arow = row0 + rlo;

  floatx4 acc[8];
#pragma unroll
  for (int ct = 0; ct < 8; ++ct) { acc[ct][0]=0.f; acc[ct][1]=0.f; acc[ct][2]=0.f; acc[ct][3]=0.f; }
  int NS = K1 >> 5;
  for (int s = 0; s < NS; ++s) {
    shortx8 a = {0,0,0,0,0,0,0,0};
    if (arow < N) a = *(const shortx8*)(in + (size_t)arow * K1 + s * 32 + quad * 8);
    const unsigned short* wp = w1z + ((size_t)(s * 8) * 64 + lane) * 8;
#pragma unroll
    for (int ct = 0; ct < 8; ++ct) {
      shortx8 b = *(const shortx8*)(wp + ct * 512);
      acc[ct] = __builtin_amdgcn_mfma_f32_16x16x32_bf16(a, b, acc[ct], 0, 0, 0);
    }
  }
#pragma unroll
  for (int ct = 0; ct < 8; ++ct) {
    float bm = b1[ct * 16 + rlo];
#pragma unroll
    for (int r = 0; r < 4; ++r) {
      float v = acc[ct][r] + bm;
      if (act1 == 1) v = v > 0.f ? v : (__expf(v) - 1.f);
      else if (act1 == 2) v = v > 0.f ? v : 0.f;
      tls[wave][quad * 4 + r][ct * 16 + rlo] = f2bf(v);
    }
  }
  __syncthreads();

  floatx4 acc2[8];
#pragma unroll
  for (int ct = 0; ct < 8; ++ct) { acc2[ct][0]=0.f; acc2[ct][1]=0.f; acc2[ct][2]=0.f; acc2[ct][3]=0.f; }
  for (int s = 0; s < 4; ++s) {
    shortx8 a = *(const shortx8*)(&tls[wave][rlo][s * 32 + quad * 8]);
    const unsigned short* wp = w2z + ((size_t)(s * 8) * 64 + lane) * 8;
#pragma unroll
    for (int ct = 0; ct < 8; ++ct) {
      shortx8 b = *(const shortx8*)(wp + ct * 512);
      acc2[ct] = __builtin_amdgcn_mfma_f32_16x16x32_bf16(a, b, acc2[ct], 0, 0, 0);
    }
  }
#pragma unroll
  for (int ct = 0; ct < 8; ++ct) {
    float bm = b2[ct * 16 + rlo];
#pragma unroll
    for (int r = 0; r < 4; ++r) {
      int rr = row0 + quad * 4 + r;
      if (rr < N) {
        float v = acc2[ct][r] + bm;
        if (act2 == 1) v = v > 0.f ? v : (__expf(v) - 1.f);
        else if (act2 == 2) v = v > 0.f ? v : 0.f;
        if (outb) outb[(size_t)rr * 128 + ct * 16 + rlo] = f2bf(v);
        else outf[(size_t)rr * 128 + ct * 16 + rlo] = v;
      }
    }
  }
}

// ---- pooling: batch sorted; wave walks 32 nodes, flushes atomics at graph edges
__global__ void k_pool(const unsigned short* __restrict__ x2, const int* __restrict__ batch,
                       float* __restrict__ hg) {
  int gt = blockIdx.x * 256 + threadIdx.x;
  int chunk = gt >> 6, lane = gt & 63;
  int n0 = chunk * 32;
  if (n0 >= NN) return;
  int nend = n0 + 32; if (nend > NN) nend = NN;
  float ax = 0.f, ay = 0.f;
  int gcur = batch[n0];
  for (int n = n0; n < nend; ++n) {
    int g = batch[n];
    if (g != gcur) {
      atomicAdd(&hg[gcur * 128 + lane * 2], ax);
      atomicAdd(&hg[gcur * 128 + lane * 2 + 1], ay);
      ax = 0.f; ay = 0.f; gcur = g;
    }
    unsigned int v = *(const unsigned int*)(x2 + (size_t)n * 128 + lane * 2);
    ax += bf2f((unsigned short)(v & 0xFFFF));
    ay += bf2f((unsigned short)(v >> 16));
  }
  atomicAdd(&hg[gcur * 128 + lane * 2], ax);
  atomicAdd(&hg[gcur * 128 + lane * 2 + 1], ay);
}

__global__ void k_cvt(const float* __restrict__ src, unsigned short* __restrict__ dstp, int n) {
  int i = blockIdx.x * 256 + threadIdx.x;
  if (i < n) dstp[i] = f2bf(src[i]);
}

extern "C" void kernel_launch(void* const* d_in, const int* in_sizes, int n_in,
                              void* d_out, int out_size, void* d_ws, size_t ws_size,
                              hipStream_t stream) {
  const int* x_idx  = (const int*)d_in[0];
  const int* e_src  = (const int*)d_in[1];
  const int* e_dst  = e_src + NE;
  const int* e_attr = (const int*)d_in[2];
  const int* batch  = (const int*)d_in[3];
  const float* atom = (const float*)d_in[4];
  const float* bond = (const float*)d_in[5];
  const float* we0  = (const float*)d_in[6];
  const float* be0  = (const float*)d_in[7];
  const float* w1_0 = (const float*)d_in[8];
  const float* b1_0 = (const float*)d_in[9];
  const float* w2_0 = (const float*)d_in[10];
  const float* b2_0 = (const float*)d_in[11];
  const float* we1  = (const float*)d_in[12];
  const float* be1  = (const float*)d_in[13];
  const float* w1_1 = (const float*)d_in[14];
  const float* b1_1 = (const float*)d_in[15];
  const float* w2_1 = (const float*)d_in[16];
  const float* b2_1 = (const float*)d_in[17];
  const float* l1w  = (const float*)d_in[18];
  const float* l1b  = (const float*)d_in[19];
  const float* l2w  = (const float*)d_in[20];
  const float* l2b  = (const float*)d_in[21];

  char* ws = (char*)d_ws;
  size_t off = 0;
  auto alloc = [&](size_t bytes) -> void* {
    void* p = ws + off;
    off = (off + bytes + 255) & ~(size_t)255;
    return p;
  };
  int* counts = (int*)alloc((size_t)NN * 4);
  int* offs   = (int*)alloc((size_t)(NN + 1) * 4);
  int* cursor = (int*)alloc((size_t)NN * 4);
  int* bsums  = (int*)alloc(512);
  float* et0  = (float*)alloc(16 * 64 * 4);
  float* et1  = (float*)alloc(16 * 128 * 4);
  float* M0   = (float*)alloc((size_t)119 * 16 * 64 * 4);
  unsigned short* w1_0z = (unsigned short*)alloc(64 * 128 * 2);
  unsigned short* w2_0z = (unsigned short*)alloc(128 * 128 * 2);
  unsigned short* w1_1z = (unsigned short*)alloc(128 * 128 * 2);
  unsigned short* w2_1z = (unsigned short*)alloc(128 * 128 * 2);
  unsigned short* l1z   = (unsigned short*)alloc(128 * 128 * 2);
  unsigned short* l2z   = (unsigned short*)alloc(128 * 128 * 2);
  int* csr = (int*)alloc((size_t)NE * 4);
  unsigned short* h0 = (unsigned short*)alloc((size_t)NN * 64 * 2);
  unsigned short* x1 = (unsigned short*)alloc((size_t)NN * 128 * 2);
  unsigned short* h1 = (unsigned short*)alloc((size_t)NN * 128 * 2);
  float* hgf = (float*)alloc((size_t)NG * 128 * 4);
  unsigned short* hgb = (unsigned short*)alloc((size_t)NG * 128 * 2);
  unsigned short* x2 = x1;  // x1 dead after agg1; reuse for layer-1 MLP output

  hipMemsetAsync(counts, 0, (size_t)NN * 4, stream);
  hipMemsetAsync(hgf, 0, (size_t)NG * 128 * 4, stream);

  k_hist<<<NE / 256, 256, 0, stream>>>(e_dst, counts);
  k_scan1<<<(NN + 1023) / 1024, 256, 0, stream>>>(counts, offs, bsums);
  k_scan2<<<1, 128, 0, stream>>>(bsums, (NN + 1023) / 1024);
  k_scan3<<<(NN + 255) / 256, 256, 0, stream>>>(offs, bsums, cursor);
  k_fill<<<NE / 256, 256, 0, stream>>>(e_src, e_dst, e_attr, x_idx, cursor, csr);
  k_et<<<12, 256, 0, stream>>>(bond, we0, be0, we1, be1, et0, et1);
  k_m0<<<(119 * 16 * 64 + 255) / 256, 256, 0, stream>>>(atom, et0, M0);
  k_swz<<<(64 * 128 + 255) / 256, 256, 0, stream>>>(w1_0, w1_0z, 64);
  k_swz<<<64, 256, 0, stream>>>(w2_0, w2_0z, 128);
  k_swz<<<64, 256, 0, stream>>>(w1_1, w1_1z, 128);
  k_swz<<<64, 256, 0, stream>>>(w2_1, w2_1z, 128);
  k_swz<<<64, 256, 0, stream>>>(l1w, l1z, 128);
  k_swz<<<64, 256, 0, stream>>>(l2w, l2z, 128);

  k_agg0<<<NN / 4, 256, 0, stream>>>(x_idx, atom, M0, offs, csr, h0);
  k_mlp<<<(NN + 63) / 64, 256, 0, stream>>>(h0, 64, w1_0z, b1_0, w2_0z, b2_0,
                                            x1, nullptr, NN, 1, 1);
  k_agg1<<<NN / 4, 256, 0, stream>>>(x1, et1, offs, csr, h1);
  k_mlp<<<(NN + 63) / 64, 256, 0, stream>>>(h1, 128, w1_1z, b1_1, w2_1z, b2_1,
                                            x2, nullptr, NN, 1, 1);
  k_pool<<<(((NN + 31) / 32) * 64 + 255) / 256, 256, 0, stream>>>(x2, batch, hgf);
  k_cvt<<<(NG * 128 + 255) / 256, 256, 0, stream>>>(hgf, hgb, NG * 128);
  k_mlp<<<(NG + 63) / 64, 256, 0, stream>>>(hgb, 128, l1z, l1b, l2z, l2b,
                                            nullptr, (float*)d_out, NG, 2, 0);
}

// Round 3
// 572.760 us; speedup vs baseline: 1.0994x; 1.0994x over previous
//
#include <hip/hip_runtime.h>
#include <hip/hip_bf16.h>

// GINE on MI355X — fp32 inputs/outputs; bf16 MFMA internals.
static const int NN = 100000;   // nodes
static const int NE = 1600000;  // edges
static const int NG = 512;      // graphs

typedef __attribute__((ext_vector_type(8))) short shortx8;
typedef __attribute__((ext_vector_type(4))) float floatx4;

__device__ __forceinline__ float bf2f(unsigned short u) {
  union { unsigned int i; float f; } v; v.i = ((unsigned int)u) << 16; return v.f;
}
__device__ __forceinline__ unsigned short f2bf(float f) {
  union { float f; unsigned int i; } v; v.f = f;
  return (unsigned short)((v.i + 0x7FFFu + ((v.i >> 16) & 1u)) >> 16);
}

// ---- CSR build ----------------------------------------------------------
__global__ void k_hist(const int* __restrict__ dst, int* __restrict__ counts) {
  int e = blockIdx.x * 256 + threadIdx.x;
  if (e < NE) atomicAdd(&counts[dst[e]], 1);
}

__global__ void k_scan1(const int* __restrict__ counts, int* __restrict__ offs,
                        int* __restrict__ bsums) {
  __shared__ int sh[256];
  int t = threadIdx.x;
  int base = blockIdx.x * 1024 + t * 4;
  int c0 = (base + 0 < NN) ? counts[base + 0] : 0;
  int c1 = (base + 1 < NN) ? counts[base + 1] : 0;
  int c2 = (base + 2 < NN) ? counts[base + 2] : 0;
  int c3 = (base + 3 < NN) ? counts[base + 3] : 0;
  int ts = c0 + c1 + c2 + c3;
  sh[t] = ts;
  __syncthreads();
  for (int d = 1; d < 256; d <<= 1) {
    int v = (t >= d) ? sh[t - d] : 0;
    __syncthreads();
    sh[t] += v;
    __syncthreads();
  }
  int run = sh[t] - ts;
  if (base + 0 < NN) offs[base + 0] = run;
  run += c0;
  if (base + 1 < NN) offs[base + 1] = run;
  run += c1;
  if (base + 2 < NN) offs[base + 2] = run;
  run += c2;
  if (base + 3 < NN) offs[base + 3] = run;
  if (t == 255) bsums[blockIdx.x] = sh[255];
}

__global__ void k_scan2(int* __restrict__ bsums, int nb) {
  __shared__ int sh[128];
  int t = threadIdx.x;
  int v = (t < nb) ? bsums[t] : 0;
  sh[t] = v;
  __syncthreads();
  for (int d = 1; d < 128; d <<= 1) {
    int u = (t >= d) ? sh[t - d] : 0;
    __syncthreads();
    sh[t] += u;
    __syncthreads();
  }
  if (t < nb) bsums[t] = sh[t] - v;
}

__global__ void k_scan3(int* __restrict__ offs, const int* __restrict__ bsums,
                        int* __restrict__ cursor) {
  int i = blockIdx.x * 256 + threadIdx.x;
  if (i < NN) {
    int o = offs[i] + bsums[i >> 10];
    offs[i] = o;
    cursor[i] = o;
  }
  if (i == 0) offs[NN] = NE;
}

// csr entry packed: src (17 bits) | (x_idx[src]*16 + edge_attr) << 17 (11 bits)
__global__ void k_fill(const int* __restrict__ src, const int* __restrict__ dstp,
                       const int* __restrict__ ea, const int* __restrict__ x_idx,
                       int* __restrict__ cursor, int* __restrict__ csr) {
  int e = blockIdx.x * 256 + threadIdx.x;
  if (e >= NE) return;
  int d = dstp[e];
  int p = atomicAdd(&cursor[d], 1);
  int s = src[e];
  csr[p] = s | ((x_idx[s] * 16 + ea[e]) << 17);
}

// ---- tiny precomputes (fp32) -------------------------------------------
__global__ void k_et(const float* __restrict__ bond,
                     const float* __restrict__ we0, const float* __restrict__ be0,
                     const float* __restrict__ we1, const float* __restrict__ be1,
                     float* __restrict__ et0, float* __restrict__ et1) {
  int i = blockIdx.x * 256 + threadIdx.x;
  if (i < 16 * 64) {
    int b = i >> 6, c = i & 63;
    float acc = be0[c];
    for (int k = 0; k < 64; ++k) acc += bond[b * 64 + k] * we0[k * 64 + c];
    et0[i] = acc;
  } else {
    int j = i - 1024;
    if (j < 16 * 128) {
      int b = j >> 7, c = j & 127;
      float acc = be1[c];
      for (int k = 0; k < 64; ++k) acc += bond[b * 64 + k] * we1[k * 128 + c];
      et1[j] = acc;
    }
  }
}

// M0[(a*16+b)*64+c] = relu(atom_emb[a][c] + et0[b][c]) -- all distinct L0 messages
__global__ void k_m0(const float* __restrict__ atom, const float* __restrict__ et0,
                     float* __restrict__ M0) {
  int i = blockIdx.x * 256 + threadIdx.x;
  if (i >= 119 * 16 * 64) return;
  int c = i & 63, b = (i >> 6) & 15, a = i >> 10;
  float v = atom[a * 64 + c] + et0[b * 64 + c];
  M0[i] = v > 0.f ? v : 0.f;
}

// fp32 weights -> bf16 MFMA B-frag order, all 6 matrices in one launch.
// wz[((s*8+ct)*64+lane)*8+j] = w[s*32+(lane>>4)*8+j][ct*16+(lane&15)]
__global__ void k_swz_all(const float* __restrict__ s0, const float* __restrict__ s1,
                          const float* __restrict__ s2, const float* __restrict__ s3,
                          const float* __restrict__ s4, const float* __restrict__ s5,
                          unsigned short* __restrict__ d0, unsigned short* __restrict__ d1,
                          unsigned short* __restrict__ d2, unsigned short* __restrict__ d3,
                          unsigned short* __restrict__ d4, unsigned short* __restrict__ d5) {
  int task = blockIdx.x >> 6;
  int i = (blockIdx.x & 63) * 256 + threadIdx.x;
  const float* w; unsigned short* wz; int K;
  switch (task) {
    case 0: w = s0; wz = d0; K = 64; break;
    case 1: w = s1; wz = d1; K = 128; break;
    case 2: w = s2; wz = d2; K = 128; break;
    case 3: w = s3; wz = d3; K = 128; break;
    case 4: w = s4; wz = d4; K = 128; break;
    default: w = s5; wz = d5; K = 128; break;
  }
  if (i >= K * 128) return;
  int j = i & 7, lane = (i >> 3) & 63, ct = (i >> 9) & 7, s = i >> 12;
  int k = s * 32 + (lane >> 4) * 8 + j;
  int m = ct * 16 + (lane & 15);
  wz[i] = f2bf(w[k * 128 + m]);
}

// ---- aggregation (gather, wave per node, lane = channel, unroll 8 for MLP)
__global__ void k_agg0(const int* __restrict__ x_idx, const float* __restrict__ atom,
                       const float* __restrict__ M0, const int* __restrict__ offs,
                       const int* __restrict__ csr, unsigned short* __restrict__ h0) {
  int gt = blockIdx.x * 256 + threadIdx.x;
  int n = gt >> 6, lane = gt & 63;
  if (n >= NN) return;
  const float* Mp = M0 + lane;
  float acc = atom[x_idx[n] * 64 + lane];  // h = x + agg (eps=0)
  int s = offs[n], e = offs[n + 1];
  int i = s;
  for (; i + 8 <= e; i += 8) {
    int p0 = csr[i + 0], p1 = csr[i + 1], p2 = csr[i + 2], p3 = csr[i + 3];
    int p4 = csr[i + 4], p5 = csr[i + 5], p6 = csr[i + 6], p7 = csr[i + 7];
    float m0 = Mp[(p0 >> 17) * 64], m1 = Mp[(p1 >> 17) * 64];
    float m2 = Mp[(p2 >> 17) * 64], m3 = Mp[(p3 >> 17) * 64];
    float m4 = Mp[(p4 >> 17) * 64], m5 = Mp[(p5 >> 17) * 64];
    float m6 = Mp[(p6 >> 17) * 64], m7 = Mp[(p7 >> 17) * 64];
    acc += ((m0 + m1) + (m2 + m3)) + ((m4 + m5) + (m6 + m7));
  }
  for (; i < e; ++i) acc += Mp[(csr[i] >> 17) * 64];
  h0[n * 64 + lane] = f2bf(acc);
}

__global__ void k_agg1(const unsigned short* __restrict__ x1, const float* __restrict__ et1,
                       const int* __restrict__ offs, const int* __restrict__ csr,
                       unsigned short* __restrict__ h1) {
  int gt = blockIdx.x * 256 + threadIdx.x;
  int n = gt >> 6, lane = gt & 63;  // lane handles channels 2c,2c+1
  if (n >= NN) return;
  const unsigned short* xp = x1 + lane * 2;
  const float* ep = et1 + lane * 2;
  unsigned int xv = *(const unsigned int*)(xp + (size_t)n * 128);
  float ax = bf2f((unsigned short)(xv & 0xFFFF));
  float ay = bf2f((unsigned short)(xv >> 16));
  int s = offs[n], e = offs[n + 1];
  int i = s;
  for (; i + 8 <= e; i += 8) {
    int p0 = csr[i + 0], p1 = csr[i + 1], p2 = csr[i + 2], p3 = csr[i + 3];
    int p4 = csr[i + 4], p5 = csr[i + 5], p6 = csr[i + 6], p7 = csr[i + 7];
    unsigned int v0 = *(const unsigned int*)(xp + (size_t)(p0 & 0x1FFFF) * 128);
    unsigned int v1 = *(const unsigned int*)(xp + (size_t)(p1 & 0x1FFFF) * 128);
    unsigned int v2 = *(const unsigned int*)(xp + (size_t)(p2 & 0x1FFFF) * 128);
    unsigned int v3 = *(const unsigned int*)(xp + (size_t)(p3 & 0x1FFFF) * 128);
    unsigned int v4 = *(const unsigned int*)(xp + (size_t)(p4 & 0x1FFFF) * 128);
    unsigned int v5 = *(const unsigned int*)(xp + (size_t)(p5 & 0x1FFFF) * 128);
    unsigned int v6 = *(const unsigned int*)(xp + (size_t)(p6 & 0x1FFFF) * 128);
    unsigned int v7 = *(const unsigned int*)(xp + (size_t)(p7 & 0x1FFFF) * 128);
    float2 e0 = *(const float2*)(ep + ((p0 >> 17) & 15) * 128);
    float2 e1 = *(const float2*)(ep + ((p1 >> 17) & 15) * 128);
    float2 e2 = *(const float2*)(ep + ((p2 >> 17) & 15) * 128);
    float2 e3 = *(const float2*)(ep + ((p3 >> 17) & 15) * 128);
    float2 e4 = *(const float2*)(ep + ((p4 >> 17) & 15) * 128);
    float2 e5 = *(const float2*)(ep + ((p5 >> 17) & 15) * 128);
    float2 e6 = *(const float2*)(ep + ((p6 >> 17) & 15) * 128);
    float2 e7 = *(const float2*)(ep + ((p7 >> 17) & 15) * 128);
    float mx, my;
    mx = bf2f((unsigned short)(v0 & 0xFFFF)) + e0.x; my = bf2f((unsigned short)(v0 >> 16)) + e0.y;
    ax += mx > 0.f ? mx : 0.f; ay += my > 0.f ? my : 0.f;
    mx = bf2f((unsigned short)(v1 & 0xFFFF)) + e1.x; my = bf2f((unsigned short)(v1 >> 16)) + e1.y;
    ax += mx > 0.f ? mx : 0.f; ay += my > 0.f ? my : 0.f;
    mx = bf2f((unsigned short)(v2 & 0xFFFF)) + e2.x; my = bf2f((unsigned short)(v2 >> 16)) + e2.y;
    ax += mx > 0.f ? mx : 0.f; ay += my > 0.f ? my : 0.f;
    mx = bf2f((unsigned short)(v3 & 0xFFFF)) + e3.x; my = bf2f((unsigned short)(v3 >> 16)) + e3.y;
    ax += mx > 0.f ? mx : 0.f; ay += my > 0.f ? my : 0.f;
    mx = bf2f((unsigned short)(v4 & 0xFFFF)) + e4.x; my = bf2f((unsigned short)(v4 >> 16)) + e4.y;
    ax += mx > 0.f ? mx : 0.f; ay += my > 0.f ? my : 0.f;
    mx = bf2f((unsigned short)(v5 & 0xFFFF)) + e5.x; my = bf2f((unsigned short)(v5 >> 16)) + e5.y;
    ax += mx > 0.f ? mx : 0.f; ay += my > 0.f ? my : 0.f;
    mx = bf2f((unsigned short)(v6 & 0xFFFF)) + e6.x; my = bf2f((unsigned short)(v6 >> 16)) + e6.y;
    ax += mx > 0.f ? mx : 0.f; ay += my > 0.f ? my : 0.f;
    mx = bf2f((unsigned short)(v7 & 0xFFFF)) + e7.x; my = bf2f((unsigned short)(v7 >> 16)) + e7.y;
    ax += mx > 0.f ? mx : 0.f; ay += my > 0.f ? my : 0.f;
  }
  for (; i < e; ++i) {
    int pc = csr[i];
    unsigned int v = *(const unsigned int*)(xp + (size_t)(pc & 0x1FFFF) * 128);
    float2 ef = *(const float2*)(ep + ((pc >> 17) & 15) * 128);
    float mx = bf2f((unsigned short)(v & 0xFFFF)) + ef.x;
    float my = bf2f((unsigned short)(v >> 16)) + ef.y;
    ax += mx > 0.f ? mx : 0.f;
    ay += my > 0.f ? my : 0.f;
  }
  unsigned int o = (unsigned int)f2bf(ax) | ((unsigned int)f2bf(ay) << 16);
  *(unsigned int*)(h1 + (size_t)n * 128 + lane * 2) = o;
}

// ---- fused double-GEMM MLP: out = act2(act1(in@w1+b1)@w2+b2)
__global__ void k_mlp(const unsigned short* __restrict__ in, int K1,
                      const unsigned short* __restrict__ w1z, const float* __restrict__ b1,
                      const unsigned short* __restrict__ w2z, const float* __restrict__ b2,
                      unsigned short* __restrict__ outb, float* __restrict__ outf,
                      int N, int act1, int act2) {
  __shared__ unsigned short tls[4][16][128];
  int lane = threadIdx.x & 63;
  int wave = threadIdx.x >> 6;
  int row0 = blockIdx.x * 64 + wave * 16;
  int rlo = lane & 15, quad = lane >> 4;
  int arow = row0 + rlo;

  floatx4 acc[8];
#pragma unroll
  for (int ct = 0; ct < 8; ++ct) { acc[ct][0]=0.f; acc[ct][1]=0.f; acc[ct][2]=0.f; acc[ct][3]=0.f; }
  int NS = K1 >> 5;
  for (int s = 0; s < NS; ++s) {
    shortx8 a = {0,0,0,0,0,0,0,0};
    if (arow < N) a = *(const shortx8*)(in + (size_t)arow * K1 + s * 32 + quad * 8);
    const unsigned short* wp = w1z + ((size_t)(s * 8) * 64 + lane) * 8;
#pragma unroll
    for (int ct = 0; ct < 8; ++ct) {
      shortx8 b = *(const shortx8*)(wp + ct * 512);
      acc[ct] = __builtin_amdgcn_mfma_f32_16x16x32_bf16(a, b, acc[ct], 0, 0, 0);
    }
  }
#pragma unroll
  for (int ct = 0; ct < 8; ++ct) {
    float bm = b1[ct * 16 + rlo];
#pragma unroll
    for (int r = 0; r < 4; ++r) {
      float v = acc[ct][r] + bm;
      if (act1 == 1) v = v > 0.f ? v : (__expf(v) - 1.f);
      else if (act1 == 2) v = v > 0.f ? v : 0.f;
      tls[wave][quad * 4 + r][ct * 16 + rlo] = f2bf(v);
    }
  }
  __syncthreads();

  floatx4 acc2[8];
#pragma unroll
  for (int ct = 0; ct < 8; ++ct) { acc2[ct][0]=0.f; acc2[ct][1]=0.f; acc2[ct][2]=0.f; acc2[ct][3]=0.f; }
  for (int s = 0; s < 4; ++s) {
    shortx8 a = *(const shortx8*)(&tls[wave][rlo][s * 32 + quad * 8]);
    const unsigned short* wp = w2z + ((size_t)(s * 8) * 64 + lane) * 8;
#pragma unroll
    for (int ct = 0; ct < 8; ++ct) {
      shortx8 b = *(const shortx8*)(wp + ct * 512);
      acc2[ct] = __builtin_amdgcn_mfma_f32_16x16x32_bf16(a, b, acc2[ct], 0, 0, 0);
    }
  }
#pragma unroll
  for (int ct = 0; ct < 8; ++ct) {
    float bm = b2[ct * 16 + rlo];
#pragma unroll
    for (int r = 0; r < 4; ++r) {
      int rr = row0 + quad * 4 + r;
      if (rr < N) {
        float v = acc2[ct][r] + bm;
        if (act2 == 1) v = v > 0.f ? v : (__expf(v) - 1.f);
        else if (act2 == 2) v = v > 0.f ? v : 0.f;
        if (outb) outb[(size_t)rr * 128 + ct * 16 + rlo] = f2bf(v);
        else outf[(size_t)rr * 128 + ct * 16 + rlo] = v;
      }
    }
  }
}

// ---- pooling: one wave per graph; batch sorted -> binary-search the range.
__global__ void k_pool(const unsigned short* __restrict__ x2, const int* __restrict__ batch,
                       unsigned short* __restrict__ hgb) {
  int g = blockIdx.x;
  int lane = threadIdx.x;  // 0..63, handles channels 2*lane, 2*lane+1
  int lo = 0, hi = NN;
  while (lo < hi) { int mid = (lo + hi) >> 1; if (batch[mid] < g) lo = mid + 1; else hi = mid; }
  int s = lo;
  hi = NN;
  while (lo < hi) { int mid = (lo + hi) >> 1; if (batch[mid] <= g) lo = mid + 1; else hi = mid; }
  int e = lo;
  float ax = 0.f, ay = 0.f;
  const unsigned short* xp = x2 + lane * 2;
  for (int n = s; n < e; ++n) {
    unsigned int v = *(const unsigned int*)(xp + (size_t)n * 128);
    ax += bf2f((unsigned short)(v & 0xFFFF));
    ay += bf2f((unsigned short)(v >> 16));
  }
  hgb[g * 128 + lane * 2] = f2bf(ax);
  hgb[g * 128 + lane * 2 + 1] = f2bf(ay);
}

extern "C" void kernel_launch(void* const* d_in, const int* in_sizes, int n_in,
                              void* d_out, int out_size, void* d_ws, size_t ws_size,
                              hipStream_t stream) {
  const int* x_idx  = (const int*)d_in[0];
  const int* e_src  = (const int*)d_in[1];
  const int* e_dst  = e_src + NE;
  const int* e_attr = (const int*)d_in[2];
  const int* batch  = (const int*)d_in[3];
  const float* atom = (const float*)d_in[4];
  const float* bond = (const float*)d_in[5];
  const float* we0  = (const float*)d_in[6];
  const float* be0  = (const float*)d_in[7];
  const float* w1_0 = (const float*)d_in[8];
  const float* b1_0 = (const float*)d_in[9];
  const float* w2_0 = (const float*)d_in[10];
  const float* b2_0 = (const float*)d_in[11];
  const float* we1  = (const float*)d_in[12];
  const float* be1  = (const float*)d_in[13];
  const float* w1_1 = (const float*)d_in[14];
  const float* b1_1 = (const float*)d_in[15];
  const float* w2_1 = (const float*)d_in[16];
  const float* b2_1 = (const float*)d_in[17];
  const float* l1w  = (const float*)d_in[18];
  const float* l1b  = (const float*)d_in[19];
  const float* l2w  = (const float*)d_in[20];
  const float* l2b  = (const float*)d_in[21];

  char* ws = (char*)d_ws;
  size_t off = 0;
  auto alloc = [&](size_t bytes) -> void* {
    void* p = ws + off;
    off = (off + bytes + 255) & ~(size_t)255;
    return p;
  };
  int* counts = (int*)alloc((size_t)NN * 4);
  int* offs   = (int*)alloc((size_t)(NN + 1) * 4);
  int* cursor = (int*)alloc((size_t)NN * 4);
  int* bsums  = (int*)alloc(512);
  float* et0  = (float*)alloc(16 * 64 * 4);
  float* et1  = (float*)alloc(16 * 128 * 4);
  float* M0   = (float*)alloc((size_t)119 * 16 * 64 * 4);
  unsigned short* w1_0z = (unsigned short*)alloc(64 * 128 * 2);
  unsigned short* w2_0z = (unsigned short*)alloc(128 * 128 * 2);
  unsigned short* w1_1z = (unsigned short*)alloc(128 * 128 * 2);
  unsigned short* w2_1z = (unsigned short*)alloc(128 * 128 * 2);
  unsigned short* l1z   = (unsigned short*)alloc(128 * 128 * 2);
  unsigned short* l2z   = (unsigned short*)alloc(128 * 128 * 2);
  int* csr = (int*)alloc((size_t)NE * 4);
  unsigned short* h0 = (unsigned short*)alloc((size_t)NN * 64 * 2);
  unsigned short* x1 = (unsigned short*)alloc((size_t)NN * 128 * 2);
  unsigned short* h1 = (unsigned short*)alloc((size_t)NN * 128 * 2);
  unsigned short* hgb = (unsigned short*)alloc((size_t)NG * 128 * 2);
  unsigned short* x2 = x1;  // x1 dead after agg1; reuse for layer-1 MLP output

  hipMemsetAsync(counts, 0, (size_t)NN * 4, stream);

  k_hist<<<NE / 256, 256, 0, stream>>>(e_dst, counts);
  k_scan1<<<(NN + 1023) / 1024, 256, 0, stream>>>(counts, offs, bsums);
  k_scan2<<<1, 128, 0, stream>>>(bsums, (NN + 1023) / 1024);
  k_scan3<<<(NN + 255) / 256, 256, 0, stream>>>(offs, bsums, cursor);
  k_fill<<<NE / 256, 256, 0, stream>>>(e_src, e_dst, e_attr, x_idx, cursor, csr);
  k_et<<<12, 256, 0, stream>>>(bond, we0, be0, we1, be1, et0, et1);
  k_m0<<<(119 * 16 * 64 + 255) / 256, 256, 0, stream>>>(atom, et0, M0);
  k_swz_all<<<384, 256, 0, stream>>>(w1_0, w2_0, w1_1, w2_1, l1w, l2w,
                                     w1_0z, w2_0z, w1_1z, w2_1z, l1z, l2z);

  k_agg0<<<NN / 4, 256, 0, stream>>>(x_idx, atom, M0, offs, csr, h0);
  k_mlp<<<(NN + 63) / 64, 256, 0, stream>>>(h0, 64, w1_0z, b1_0, w2_0z, b2_0,
                                            x1, nullptr, NN, 1, 1);
  k_agg1<<<NN / 4, 256, 0, stream>>>(x1, et1, offs, csr, h1);
  k_mlp<<<(NN + 63) / 64, 256, 0, stream>>>(h1, 128, w1_1z, b1_1, w2_1z, b2_1,
                                            x2, nullptr, NN, 1, 1);
  k_pool<<<NG, 64, 0, stream>>>(x2, batch, hgb);
  k_mlp<<<(NG + 63) / 64, 256, 0, stream>>>(hgb, 128, l1z, l1b, l2z, l2b,
                                            nullptr, (float*)d_out, NG, 2, 0);
}

// Round 4
// 463.550 us; speedup vs baseline: 1.3584x; 1.2356x over previous
//
#include <hip/hip_runtime.h>
#include <hip/hip_bf16.h>

// GINE on MI355X — fp32 inputs/outputs; bf16 MFMA internals.
static const int NN = 100000;   // nodes
static const int NE = 1600000;  // edges
static const int NG = 512;      // graphs
static const int NB = 391;      // coarse buckets of 256 nodes (dst >> 8)

typedef __attribute__((ext_vector_type(8))) short shortx8;
typedef __attribute__((ext_vector_type(4))) float floatx4;

__device__ __forceinline__ float bf2f(unsigned short u) {
  union { unsigned int i; float f; } v; v.i = ((unsigned int)u) << 16; return v.f;
}
__device__ __forceinline__ unsigned short f2bf(float f) {
  union { float f; unsigned int i; } v; v.f = f;
  return (unsigned short)((v.i + 0x7FFFu + ((v.i >> 16) & 1u)) >> 16);
}

// ---- CSR build: two-level bucket sort ----------------------------------
// Pass A: coarse histogram (LDS-staged; one global atomic per WG x bucket)
__global__ void k_bhist(const int* __restrict__ dst, int* __restrict__ bcount) {
  __shared__ int cnt[NB];
  for (int i = threadIdx.x; i < NB; i += 256) cnt[i] = 0;
  __syncthreads();
  int base = blockIdx.x * 16384;
  for (int k = 0; k < 64; ++k) {
    int e = base + k * 256 + threadIdx.x;
    if (e < NE) atomicAdd(&cnt[dst[e] >> 8], 1);
  }
  __syncthreads();
  for (int i = threadIdx.x; i < NB; i += 256)
    if (cnt[i]) atomicAdd(&bcount[i], cnt[i]);
}

// Scan of 391 bucket counts -> bucket offsets bo, cursor init, offs[NN]=NE.
__global__ void k_bscan(const int* __restrict__ bcount, int* __restrict__ bo,
                        int* __restrict__ bcursor, int* __restrict__ offs) {
  __shared__ int sh[512];
  int t = threadIdx.x;
  int c0 = (t < NB) ? bcount[t] : 0;
  int c1 = (t + 256 < NB) ? bcount[t + 256] : 0;
  sh[t] = c0; sh[t + 256] = c1;
  __syncthreads();
  for (int d = 1; d < 512; d <<= 1) {
    int v0 = (t >= d) ? sh[t - d] : 0;
    int v1 = (t + 256 >= d) ? sh[t + 256 - d] : 0;
    __syncthreads();
    sh[t] += v0; sh[t + 256] += v1;
    __syncthreads();
  }
  if (t < NB) { int e0 = sh[t] - c0; bo[t] = e0; bcursor[t] = e0; }
  int u = t + 256;
  if (u < NB) { int e0 = sh[u] - c1; bo[u] = e0; bcursor[u] = e0; }
  if (t == 0) offs[NN] = NE;
}

// Pass B: bin 4096-edge chunks by coarse bucket; LDS-grouped, coalesced run writes.
// pair = (dst, payload) where payload = src | ((x_idx[src]*16 + ea) << 17).
__global__ void k_bin(const int* __restrict__ src, const int* __restrict__ dstp,
                      const int* __restrict__ ea, const int* __restrict__ x_idx,
                      int* __restrict__ bcursor, uint2* __restrict__ pairs) {
  __shared__ int cnt[512];
  __shared__ int incl[512];
  __shared__ int cur[NB];
  __shared__ int rbase[NB];
  __shared__ uint2 stage[4096];
  int t = threadIdx.x;
  int e0 = blockIdx.x * 4096;
  int ecnt = NE - e0; if (ecnt > 4096) ecnt = 4096;
  cnt[t] = 0; cnt[t + 256] = 0;
  __syncthreads();
  for (int k = 0; k < 16; ++k) {
    int i = k * 256 + t;
    if (i < ecnt) atomicAdd(&cnt[dstp[e0 + i] >> 8], 1);
  }
  __syncthreads();
  incl[t] = cnt[t]; incl[t + 256] = cnt[t + 256];
  __syncthreads();
  for (int d = 1; d < 512; d <<= 1) {
    int v0 = (t >= d) ? incl[t - d] : 0;
    int v1 = (t + 256 >= d) ? incl[t + 256 - d] : 0;
    __syncthreads();
    incl[t] += v0; incl[t + 256] += v1;
    __syncthreads();
  }
  if (t < NB) { cur[t] = incl[t] - cnt[t]; if (cnt[t]) rbase[t] = atomicAdd(&bcursor[t], cnt[t]); }
  int u = t + 256;
  if (u < NB) { cur[u] = incl[u] - cnt[u]; if (cnt[u]) rbase[u] = atomicAdd(&bcursor[u], cnt[u]); }
  __syncthreads();
  for (int k = 0; k < 16; ++k) {
    int i = k * 256 + t;
    if (i < ecnt) {
      int e = e0 + i;
      int d = dstp[e];
      int s = src[e];
      unsigned int pk = (unsigned int)s | ((unsigned int)(x_idx[s] * 16 + ea[e]) << 17);
      int p = atomicAdd(&cur[d >> 8], 1);
      stage[p] = make_uint2((unsigned int)d, pk);
    }
  }
  __syncthreads();
  for (int j = t; j < ecnt; j += 256) {
    int lo = 0, hi = NB - 1;  // smallest b with incl[b] > j
    while (lo < hi) { int mid = (lo + hi) >> 1; if (incl[mid] > j) hi = mid; else lo = mid + 1; }
    int excl = incl[lo] - cnt[lo];
    pairs[rbase[lo] + (j - excl)] = stage[j];
  }
}

// Pass C: fine counting-sort within each bucket; writes land in one ~16KB
// window owned by this WG (single-XCD dirty lines). Also emits per-node offs.
__global__ void k_fine(const uint2* __restrict__ pairs, const int* __restrict__ bo,
                       int* __restrict__ offs, int* __restrict__ csr) {
  __shared__ int cnt[256];
  __shared__ int incl[256];
  __shared__ int cur[256];
  int b = blockIdx.x;
  int t = threadIdx.x;
  int start = bo[b];
  int end = (b == NB - 1) ? NE : bo[b + 1];
  int base_n = b << 8;
  cnt[t] = 0;
  __syncthreads();
  for (int j = start + t; j < end; j += 256)
    atomicAdd(&cnt[(int)pairs[j].x - base_n], 1);
  __syncthreads();
  incl[t] = cnt[t];
  __syncthreads();
  for (int d = 1; d < 256; d <<= 1) {
    int v = (t >= d) ? incl[t - d] : 0;
    __syncthreads();
    incl[t] += v;
    __syncthreads();
  }
  int excl = incl[t] - cnt[t];
  cur[t] = excl;
  int node = base_n + t;
  if (node < NN) offs[node] = start + excl;
  __syncthreads();
  for (int j = start + t; j < end; j += 256) {
    uint2 p = pairs[j];
    int pos = start + atomicAdd(&cur[(int)p.x - base_n], 1);
    csr[pos] = (int)p.y;
  }
}

// ---- tiny precomputes (fp32) -------------------------------------------
__global__ void k_et(const float* __restrict__ bond,
                     const float* __restrict__ we0, const float* __restrict__ be0,
                     const float* __restrict__ we1, const float* __restrict__ be1,
                     float* __restrict__ et0, float* __restrict__ et1) {
  int i = blockIdx.x * 256 + threadIdx.x;
  if (i < 16 * 64) {
    int b = i >> 6, c = i & 63;
    float acc = be0[c];
    for (int k = 0; k < 64; ++k) acc += bond[b * 64 + k] * we0[k * 64 + c];
    et0[i] = acc;
  } else {
    int j = i - 1024;
    if (j < 16 * 128) {
      int b = j >> 7, c = j & 127;
      float acc = be1[c];
      for (int k = 0; k < 64; ++k) acc += bond[b * 64 + k] * we1[k * 128 + c];
      et1[j] = acc;
    }
  }
}

// M0[(a*16+b)*64+c] = relu(atom_emb[a][c] + et0[b][c]) -- all distinct L0 messages
__global__ void k_m0(const float* __restrict__ atom, const float* __restrict__ et0,
                     float* __restrict__ M0) {
  int i = blockIdx.x * 256 + threadIdx.x;
  if (i >= 119 * 16 * 64) return;
  int c = i & 63, b = (i >> 6) & 15, a = i >> 10;
  float v = atom[a * 64 + c] + et0[b * 64 + c];
  M0[i] = v > 0.f ? v : 0.f;
}

// fp32 weights -> bf16 MFMA B-frag order, all 6 matrices in one launch.
__global__ void k_swz_all(const float* __restrict__ s0, const float* __restrict__ s1,
                          const float* __restrict__ s2, const float* __restrict__ s3,
                          const float* __restrict__ s4, const float* __restrict__ s5,
                          unsigned short* __restrict__ d0, unsigned short* __restrict__ d1,
                          unsigned short* __restrict__ d2, unsigned short* __restrict__ d3,
                          unsigned short* __restrict__ d4, unsigned short* __restrict__ d5) {
  int task = blockIdx.x >> 6;
  int i = (blockIdx.x & 63) * 256 + threadIdx.x;
  const float* w; unsigned short* wz; int K;
  switch (task) {
    case 0: w = s0; wz = d0; K = 64; break;
    case 1: w = s1; wz = d1; K = 128; break;
    case 2: w = s2; wz = d2; K = 128; break;
    case 3: w = s3; wz = d3; K = 128; break;
    case 4: w = s4; wz = d4; K = 128; break;
    default: w = s5; wz = d5; K = 128; break;
  }
  if (i >= K * 128) return;
  int j = i & 7, lane = (i >> 3) & 63, ct = (i >> 9) & 7, s = i >> 12;
  int k = s * 32 + (lane >> 4) * 8 + j;
  int m = ct * 16 + (lane & 15);
  wz[i] = f2bf(w[k * 128 + m]);
}

// ---- aggregation (gather, wave per node, lane = channel, unroll 8)
__global__ void k_agg0(const int* __restrict__ x_idx, const float* __restrict__ atom,
                       const float* __restrict__ M0, const int* __restrict__ offs,
                       const int* __restrict__ csr, unsigned short* __restrict__ h0) {
  int gt = blockIdx.x * 256 + threadIdx.x;
  int n = gt >> 6, lane = gt & 63;
  if (n >= NN) return;
  const float* Mp = M0 + lane;
  float acc = atom[x_idx[n] * 64 + lane];  // h = x + agg (eps=0)
  int s = offs[n], e = offs[n + 1];
  int i = s;
  for (; i + 8 <= e; i += 8) {
    int p0 = csr[i + 0], p1 = csr[i + 1], p2 = csr[i + 2], p3 = csr[i + 3];
    int p4 = csr[i + 4], p5 = csr[i + 5], p6 = csr[i + 6], p7 = csr[i + 7];
    float m0 = Mp[(p0 >> 17) * 64], m1 = Mp[(p1 >> 17) * 64];
    float m2 = Mp[(p2 >> 17) * 64], m3 = Mp[(p3 >> 17) * 64];
    float m4 = Mp[(p4 >> 17) * 64], m5 = Mp[(p5 >> 17) * 64];
    float m6 = Mp[(p6 >> 17) * 64], m7 = Mp[(p7 >> 17) * 64];
    acc += ((m0 + m1) + (m2 + m3)) + ((m4 + m5) + (m6 + m7));
  }
  for (; i < e; ++i) acc += Mp[(csr[i] >> 17) * 64];
  h0[n * 64 + lane] = f2bf(acc);
}

__global__ void k_agg1(const unsigned short* __restrict__ x1, const float* __restrict__ et1,
                       const int* __restrict__ offs, const int* __restrict__ csr,
                       unsigned short* __restrict__ h1) {
  int gt = blockIdx.x * 256 + threadIdx.x;
  int n = gt >> 6, lane = gt & 63;  // lane handles channels 2c,2c+1
  if (n >= NN) return;
  const unsigned short* xp = x1 + lane * 2;
  const float* ep = et1 + lane * 2;
  unsigned int xv = *(const unsigned int*)(xp + (size_t)n * 128);
  float ax = bf2f((unsigned short)(xv & 0xFFFF));
  float ay = bf2f((unsigned short)(xv >> 16));
  int s = offs[n], e = offs[n + 1];
  int i = s;
  for (; i + 8 <= e; i += 8) {
    int p0 = csr[i + 0], p1 = csr[i + 1], p2 = csr[i + 2], p3 = csr[i + 3];
    int p4 = csr[i + 4], p5 = csr[i + 5], p6 = csr[i + 6], p7 = csr[i + 7];
    unsigned int v0 = *(const unsigned int*)(xp + (size_t)(p0 & 0x1FFFF) * 128);
    unsigned int v1 = *(const unsigned int*)(xp + (size_t)(p1 & 0x1FFFF) * 128);
    unsigned int v2 = *(const unsigned int*)(xp + (size_t)(p2 & 0x1FFFF) * 128);
    unsigned int v3 = *(const unsigned int*)(xp + (size_t)(p3 & 0x1FFFF) * 128);
    unsigned int v4 = *(const unsigned int*)(xp + (size_t)(p4 & 0x1FFFF) * 128);
    unsigned int v5 = *(const unsigned int*)(xp + (size_t)(p5 & 0x1FFFF) * 128);
    unsigned int v6 = *(const unsigned int*)(xp + (size_t)(p6 & 0x1FFFF) * 128);
    unsigned int v7 = *(const unsigned int*)(xp + (size_t)(p7 & 0x1FFFF) * 128);
    float2 e0 = *(const float2*)(ep + ((p0 >> 17) & 15) * 128);
    float2 e1 = *(const float2*)(ep + ((p1 >> 17) & 15) * 128);
    float2 e2 = *(const float2*)(ep + ((p2 >> 17) & 15) * 128);
    float2 e3 = *(const float2*)(ep + ((p3 >> 17) & 15) * 128);
    float2 e4 = *(const float2*)(ep + ((p4 >> 17) & 15) * 128);
    float2 e5 = *(const float2*)(ep + ((p5 >> 17) & 15) * 128);
    float2 e6 = *(const float2*)(ep + ((p6 >> 17) & 15) * 128);
    float2 e7 = *(const float2*)(ep + ((p7 >> 17) & 15) * 128);
    float mx, my;
    mx = bf2f((unsigned short)(v0 & 0xFFFF)) + e0.x; my = bf2f((unsigned short)(v0 >> 16)) + e0.y;
    ax += mx > 0.f ? mx : 0.f; ay += my > 0.f ? my : 0.f;
    mx = bf2f((unsigned short)(v1 & 0xFFFF)) + e1.x; my = bf2f((unsigned short)(v1 >> 16)) + e1.y;
    ax += mx > 0.f ? mx : 0.f; ay += my > 0.f ? my : 0.f;
    mx = bf2f((unsigned short)(v2 & 0xFFFF)) + e2.x; my = bf2f((unsigned short)(v2 >> 16)) + e2.y;
    ax += mx > 0.f ? mx : 0.f; ay += my > 0.f ? my : 0.f;
    mx = bf2f((unsigned short)(v3 & 0xFFFF)) + e3.x; my = bf2f((unsigned short)(v3 >> 16)) + e3.y;
    ax += mx > 0.f ? mx : 0.f; ay += my > 0.f ? my : 0.f;
    mx = bf2f((unsigned short)(v4 & 0xFFFF)) + e4.x; my = bf2f((unsigned short)(v4 >> 16)) + e4.y;
    ax += mx > 0.f ? mx : 0.f; ay += my > 0.f ? my : 0.f;
    mx = bf2f((unsigned short)(v5 & 0xFFFF)) + e5.x; my = bf2f((unsigned short)(v5 >> 16)) + e5.y;
    ax += mx > 0.f ? mx : 0.f; ay += my > 0.f ? my : 0.f;
    mx = bf2f((unsigned short)(v6 & 0xFFFF)) + e6.x; my = bf2f((unsigned short)(v6 >> 16)) + e6.y;
    ax += mx > 0.f ? mx : 0.f; ay += my > 0.f ? my : 0.f;
    mx = bf2f((unsigned short)(v7 & 0xFFFF)) + e7.x; my = bf2f((unsigned short)(v7 >> 16)) + e7.y;
    ax += mx > 0.f ? mx : 0.f; ay += my > 0.f ? my : 0.f;
  }
  for (; i < e; ++i) {
    int pc = csr[i];
    unsigned int v = *(const unsigned int*)(xp + (size_t)(pc & 0x1FFFF) * 128);
    float2 ef = *(const float2*)(ep + ((pc >> 17) & 15) * 128);
    float mx = bf2f((unsigned short)(v & 0xFFFF)) + ef.x;
    float my = bf2f((unsigned short)(v >> 16)) + ef.y;
    ax += mx > 0.f ? mx : 0.f;
    ay += my > 0.f ? my : 0.f;
  }
  unsigned int o = (unsigned int)f2bf(ax) | ((unsigned int)f2bf(ay) << 16);
  *(unsigned int*)(h1 + (size_t)n * 128 + lane * 2) = o;
}

// ---- fused double-GEMM MLP: out = act2(act1(in@w1+b1)@w2+b2)
__global__ void k_mlp(const unsigned short* __restrict__ in, int K1,
                      const unsigned short* __restrict__ w1z, const float* __restrict__ b1,
                      const unsigned short* __restrict__ w2z, const float* __restrict__ b2,
                      unsigned short* __restrict__ outb, float* __restrict__ outf,
                      int N, int act1, int act2) {
  __shared__ unsigned short tls[4][16][128];
  int lane = threadIdx.x & 63;
  int wave = threadIdx.x >> 6;
  int row0 = blockIdx.x * 64 + wave * 16;
  int rlo = lane & 15, quad = lane >> 4;
  int arow = row0 + rlo;

  floatx4 acc[8];
#pragma unroll
  for (int ct = 0; ct < 8; ++ct) { acc[ct][0]=0.f; acc[ct][1]=0.f; acc[ct][2]=0.f; acc[ct][3]=0.f; }
  int NS = K1 >> 5;
  for (int s = 0; s < NS; ++s) {
    shortx8 a = {0,0,0,0,0,0,0,0};
    if (arow < N) a = *(const shortx8*)(in + (size_t)arow * K1 + s * 32 + quad * 8);
    const unsigned short* wp = w1z + ((size_t)(s * 8) * 64 + lane) * 8;
#pragma unroll
    for (int ct = 0; ct < 8; ++ct) {
      shortx8 b = *(const shortx8*)(wp + ct * 512);
      acc[ct] = __builtin_amdgcn_mfma_f32_16x16x32_bf16(a, b, acc[ct], 0, 0, 0);
    }
  }
#pragma unroll
  for (int ct = 0; ct < 8; ++ct) {
    float bm = b1[ct * 16 + rlo];
#pragma unroll
    for (int r = 0; r < 4; ++r) {
      float v = acc[ct][r] + bm;
      if (act1 == 1) v = v > 0.f ? v : (__expf(v) - 1.f);
      else if (act1 == 2) v = v > 0.f ? v : 0.f;
      tls[wave][quad * 4 + r][ct * 16 + rlo] = f2bf(v);
    }
  }
  __syncthreads();

  floatx4 acc2[8];
#pragma unroll
  for (int ct = 0; ct < 8; ++ct) { acc2[ct][0]=0.f; acc2[ct][1]=0.f; acc2[ct][2]=0.f; acc2[ct][3]=0.f; }
  for (int s = 0; s < 4; ++s) {
    shortx8 a = *(const shortx8*)(&tls[wave][rlo][s * 32 + quad * 8]);
    const unsigned short* wp = w2z + ((size_t)(s * 8) * 64 + lane) * 8;
#pragma unroll
    for (int ct = 0; ct < 8; ++ct) {
      shortx8 b = *(const shortx8*)(wp + ct * 512);
      acc2[ct] = __builtin_amdgcn_mfma_f32_16x16x32_bf16(a, b, acc2[ct], 0, 0, 0);
    }
  }
#pragma unroll
  for (int ct = 0; ct < 8; ++ct) {
    float bm = b2[ct * 16 + rlo];
#pragma unroll
    for (int r = 0; r < 4; ++r) {
      int rr = row0 + quad * 4 + r;
      if (rr < N) {
        float v = acc2[ct][r] + bm;
        if (act2 == 1) v = v > 0.f ? v : (__expf(v) - 1.f);
        else if (act2 == 2) v = v > 0.f ? v : 0.f;
        if (outb) outb[(size_t)rr * 128 + ct * 16 + rlo] = f2bf(v);
        else outf[(size_t)rr * 128 + ct * 16 + rlo] = v;
      }
    }
  }
}

// ---- pooling: one wave per graph; batch sorted -> binary-search the range.
__global__ void k_pool(const unsigned short* __restrict__ x2, const int* __restrict__ batch,
                       unsigned short* __restrict__ hgb) {
  int g = blockIdx.x;
  int lane = threadIdx.x;  // 0..63, handles channels 2*lane, 2*lane+1
  int lo = 0, hi = NN;
  while (lo < hi) { int mid = (lo + hi) >> 1; if (batch[mid] < g) lo = mid + 1; else hi = mid; }
  int s = lo;
  hi = NN;
  while (lo < hi) { int mid = (lo + hi) >> 1; if (batch[mid] <= g) lo = mid + 1; else hi = mid; }
  int e = lo;
  float ax = 0.f, ay = 0.f;
  const unsigned short* xp = x2 + lane * 2;
  for (int n = s; n < e; ++n) {
    unsigned int v = *(const unsigned int*)(xp + (size_t)n * 128);
    ax += bf2f((unsigned short)(v & 0xFFFF));
    ay += bf2f((unsigned short)(v >> 16));
  }
  hgb[g * 128 + lane * 2] = f2bf(ax);
  hgb[g * 128 + lane * 2 + 1] = f2bf(ay);
}

extern "C" void kernel_launch(void* const* d_in, const int* in_sizes, int n_in,
                              void* d_out, int out_size, void* d_ws, size_t ws_size,
                              hipStream_t stream) {
  const int* x_idx  = (const int*)d_in[0];
  const int* e_src  = (const int*)d_in[1];
  const int* e_dst  = e_src + NE;
  const int* e_attr = (const int*)d_in[2];
  const int* batch  = (const int*)d_in[3];
  const float* atom = (const float*)d_in[4];
  const float* bond = (const float*)d_in[5];
  const float* we0  = (const float*)d_in[6];
  const float* be0  = (const float*)d_in[7];
  const float* w1_0 = (const float*)d_in[8];
  const float* b1_0 = (const float*)d_in[9];
  const float* w2_0 = (const float*)d_in[10];
  const float* b2_0 = (const float*)d_in[11];
  const float* we1  = (const float*)d_in[12];
  const float* be1  = (const float*)d_in[13];
  const float* w1_1 = (const float*)d_in[14];
  const float* b1_1 = (const float*)d_in[15];
  const float* w2_1 = (const float*)d_in[16];
  const float* b2_1 = (const float*)d_in[17];
  const float* l1w  = (const float*)d_in[18];
  const float* l1b  = (const float*)d_in[19];
  const float* l2w  = (const float*)d_in[20];
  const float* l2b  = (const float*)d_in[21];

  char* ws = (char*)d_ws;
  size_t off = 0;
  auto alloc = [&](size_t bytes) -> void* {
    void* p = ws + off;
    off = (off + bytes + 255) & ~(size_t)255;
    return p;
  };
  int* bcount  = (int*)alloc((size_t)NB * 4);
  int* bo      = (int*)alloc((size_t)NB * 4);
  int* bcursor = (int*)alloc((size_t)NB * 4);
  int* offs    = (int*)alloc((size_t)(NN + 1) * 4);
  float* et0   = (float*)alloc(16 * 64 * 4);
  float* et1   = (float*)alloc(16 * 128 * 4);
  float* M0    = (float*)alloc((size_t)119 * 16 * 64 * 4);
  unsigned short* w1_0z = (unsigned short*)alloc(64 * 128 * 2);
  unsigned short* w2_0z = (unsigned short*)alloc(128 * 128 * 2);
  unsigned short* w1_1z = (unsigned short*)alloc(128 * 128 * 2);
  unsigned short* w2_1z = (unsigned short*)alloc(128 * 128 * 2);
  unsigned short* l1z   = (unsigned short*)alloc(128 * 128 * 2);
  unsigned short* l2z   = (unsigned short*)alloc(128 * 128 * 2);
  uint2* pairs = (uint2*)alloc((size_t)NE * 8);
  int* csr = (int*)alloc((size_t)NE * 4);
  unsigned short* h0 = (unsigned short*)alloc((size_t)NN * 64 * 2);
  unsigned short* x1 = (unsigned short*)alloc((size_t)NN * 128 * 2);
  unsigned short* h1 = (unsigned short*)alloc((size_t)NN * 128 * 2);
  unsigned short* hgb = (unsigned short*)alloc((size_t)NG * 128 * 2);
  unsigned short* x2 = x1;  // x1 dead after agg1; reuse for layer-1 MLP output

  hipMemsetAsync(bcount, 0, (size_t)NB * 4, stream);

  k_bhist<<<(NE + 16383) / 16384, 256, 0, stream>>>(e_dst, bcount);
  k_bscan<<<1, 256, 0, stream>>>(bcount, bo, bcursor, offs);
  k_bin<<<(NE + 4095) / 4096, 256, 0, stream>>>(e_src, e_dst, e_attr, x_idx, bcursor, pairs);
  k_fine<<<NB, 256, 0, stream>>>(pairs, bo, offs, csr);
  k_et<<<12, 256, 0, stream>>>(bond, we0, be0, we1, be1, et0, et1);
  k_m0<<<(119 * 16 * 64 + 255) / 256, 256, 0, stream>>>(atom, et0, M0);
  k_swz_all<<<384, 256, 0, stream>>>(w1_0, w2_0, w1_1, w2_1, l1w, l2w,
                                     w1_0z, w2_0z, w1_1z, w2_1z, l1z, l2z);

  k_agg0<<<NN / 4, 256, 0, stream>>>(x_idx, atom, M0, offs, csr, h0);
  k_mlp<<<(NN + 63) / 64, 256, 0, stream>>>(h0, 64, w1_0z, b1_0, w2_0z, b2_0,
                                            x1, nullptr, NN, 1, 1);
  k_agg1<<<NN / 4, 256, 0, stream>>>(x1, et1, offs, csr, h1);
  k_mlp<<<(NN + 63) / 64, 256, 0, stream>>>(h1, 128, w1_1z, b1_1, w2_1z, b2_1,
                                            x2, nullptr, NN, 1, 1);
  k_pool<<<NG, 64, 0, stream>>>(x2, batch, hgb);
  k_mlp<<<(NG + 63) / 64, 256, 0, stream>>>(hgb, 128, l1z, l1b, l2z, l2b,
                                            nullptr, (float*)d_out, NG, 2, 0);
}